// Round 1
// baseline (56.454 us; speedup 1.0000x reference)
//
#include <hip/hip_runtime.h>

// Problem constants (B,C,H,W = 8,1,88,128; TIMESTEPS=1000)
static constexpr int N       = 8 * 1 * 88 * 128;   // 90112 pixels
static constexpr int VEC     = 4;
static constexpr int NV      = N / VEC;            // 22528 float4s
static constexpr int THREADS = 256;
static constexpr int BLOCKS  = NV / THREADS;       // 88 blocks, exact

// idx(x) = int(max(x*1000 - 1, 0)); use _rn intrinsics to forbid FMA
// contraction so quantization boundaries bit-match numpy's mul-then-sub.
__device__ __forceinline__ int bucket(float x) {
    float v = __fsub_rn(__fmul_rn(x, 1000.0f), 1.0f);
    v = fmaxf(v, 0.0f);
    return (int)v;   // truncation toward zero == astype(int32) for v >= 0
}

__global__ __launch_bounds__(THREADS) void mismatch_kernel(
        const float4* __restrict__ r, const float4* __restrict__ t,
        int* __restrict__ partial) {
    const int i = blockIdx.x * THREADS + threadIdx.x;   // 0..NV-1, exact fit
    const float4 rv = r[i];
    const float4 tv = t[i];
    int c = (bucket(rv.x) != bucket(tv.x))
          + (bucket(rv.y) != bucket(tv.y))
          + (bucket(rv.z) != bucket(tv.z))
          + (bucket(rv.w) != bucket(tv.w));
    // wave (64-lane) shuffle reduction
    #pragma unroll
    for (int off = 32; off > 0; off >>= 1)
        c += __shfl_down(c, off, 64);
    __shared__ int smem[THREADS / 64];
    if ((threadIdx.x & 63) == 0) smem[threadIdx.x >> 6] = c;
    __syncthreads();
    if (threadIdx.x == 0) {
        int s = 0;
        #pragma unroll
        for (int w = 0; w < THREADS / 64; ++w) s += smem[w];
        partial[blockIdx.x] = s;   // every slot written each launch (poison-safe)
    }
}

__global__ __launch_bounds__(128) void finalize_kernel(
        const int* __restrict__ partial, float* __restrict__ out) {
    int c = (threadIdx.x < BLOCKS) ? partial[threadIdx.x] : 0;
    #pragma unroll
    for (int off = 32; off > 0; off >>= 1)
        c += __shfl_down(c, off, 64);
    __shared__ int smem[2];
    if ((threadIdx.x & 63) == 0) smem[threadIdx.x >> 6] = c;
    __syncthreads();
    if (threadIdx.x == 0) {
        const int M = smem[0] + smem[1];
        // loss = M/(N*999) + M/N  (zero_loss + nonzero_loss), fp64 then round
        const double invN = 1.0 / (double)N;
        out[0] = (float)((double)M * (invN / 999.0 + invN));
    }
}

extern "C" void kernel_launch(void* const* d_in, const int* in_sizes, int n_in,
                              void* d_out, int out_size, void* d_ws, size_t ws_size,
                              hipStream_t stream) {
    const float4* r = (const float4*)d_in[0];  // reconstructed_image, fp32
    const float4* t = (const float4*)d_in[1];  // target_image, fp32
    int* partial = (int*)d_ws;                 // 88 ints of scratch
    float* out = (float*)d_out;                // scalar fp32 loss

    mismatch_kernel<<<BLOCKS, THREADS, 0, stream>>>(r, t, partial);
    finalize_kernel<<<1, 128, 0, stream>>>(partial, out);
}